// Round 5
// baseline (201.564 us; speedup 1.0000x reference)
//
#include <hip/hip_runtime.h>

// SaltAndPepper: out = where(mask==0, 0, where(mask==1, 1, image))
// image: (32,3,512,512) f32, mask: (32,1,512,512) i32 broadcast over C.
//
// R2 post-mortem: 63.5 us/dispatch @ 2.6 TB/s HBM, VALUBusy 7% -> latency/
// churn bound (1 load-pair per thread, 24576 short blocks). R3/R4: unroll x4
// per thread (8 outstanding loads/wave before first store) + nontemporal
// stores so the write-once output doesn't evict image/mask from the 256 MiB
// L3. R4 fix: __builtin_nontemporal_store requires a NATIVE vector type,
// not HIP_vector_type float4 -> use ext_vector_type(4).

constexpr int B  = 32;
constexpr int C  = 3;
constexpr int HW = 512 * 512;                 // 262144 pixels per plane
constexpr int G_PER_PLANE = HW / 4;           // 65536 float4 groups (2^16)
constexpr int TOTAL_G = B * C * G_PER_PLANE;  // 6,291,456
constexpr int U = 4;                          // groups per thread
constexpr int BLOCK = 256;
constexpr int G_PER_BLOCK = BLOCK * U;        // 1024 groups / block

typedef float nt_f4 __attribute__((ext_vector_type(4)));
typedef int   nt_i4 __attribute__((ext_vector_type(4)));

__global__ __launch_bounds__(BLOCK)
void sp_kernel(const float* __restrict__ img,
               const int*   __restrict__ mask,
               float*       __restrict__ out) {
    const int base = blockIdx.x * G_PER_BLOCK + threadIdx.x;

    int   t[U];
    nt_i4 m[U];
    nt_f4 v[U];

    // Issue all 8 loads before any use: max memory-level parallelism.
    #pragma unroll
    for (int k = 0; k < U; ++k) {
        t[k] = base + k * BLOCK;              // coalesced within wave
        const int plane = t[k] >> 16;         // b*C + c, in [0, 96)
        const int b     = plane / 3;
        const int g     = t[k] & (G_PER_PLANE - 1);
        m[k] = *(const nt_i4*)(mask + (size_t)b * HW + (size_t)g * 4);
        v[k] = *(const nt_f4*)(img + (size_t)t[k] * 4);
    }

    #pragma unroll
    for (int k = 0; k < U; ++k) {
        nt_f4 r;
        r.x = (m[k].x == 0) ? 0.0f : ((m[k].x == 1) ? 1.0f : v[k].x);
        r.y = (m[k].y == 0) ? 0.0f : ((m[k].y == 1) ? 1.0f : v[k].y);
        r.z = (m[k].z == 0) ? 0.0f : ((m[k].z == 1) ? 1.0f : v[k].z);
        r.w = (m[k].w == 0) ? 0.0f : ((m[k].w == 1) ? 1.0f : v[k].w);
        __builtin_nontemporal_store(r, (nt_f4*)(out + (size_t)t[k] * 4));
    }
}

extern "C" void kernel_launch(void* const* d_in, const int* in_sizes, int n_in,
                              void* d_out, int out_size, void* d_ws, size_t ws_size,
                              hipStream_t stream) {
    const float* img  = (const float*)d_in[0];
    const int*   mask = (const int*)d_in[1];
    float*       out  = (float*)d_out;

    const int grid = TOTAL_G / G_PER_BLOCK;   // 6144 blocks, exact
    sp_kernel<<<grid, BLOCK, 0, stream>>>(img, mask, out);
}